// Round 9
// baseline (154.078 us; speedup 1.0000x reference)
//
#include <hip/hip_runtime.h>

namespace {

typedef __attribute__((ext_vector_type(8))) short short8v;
typedef __attribute__((ext_vector_type(4))) float f32x4;
typedef __attribute__((ext_vector_type(4))) unsigned int uint4v;

constexpr int kB = 8;
constexpr int kS = 1024;
constexpr int kSUB = 768;
constexpr int kL = 4096;                                   // P*G
constexpr float kQScale = 0.25f * 1.44269504088896340736f; // SCALING*log2(e)
constexpr float kLamInit = 0.2f;
constexpr float kOutScale = 0.8f;
constexpr float kShift = 64.f;  // fixed softmax shift (log2 units); |score|<<60

// barrier that does NOT drain vmcnt: LDS ordering only (T4: never vmcnt(0)
// inside the loop; global stores stay in flight).
#define BAR_LGKM() asm volatile("s_waitcnt lgkmcnt(0)\ns_barrier" ::: "memory")

__device__ __forceinline__ unsigned short f2bf(float x) {
  unsigned u = __float_as_uint(x);
  return (unsigned short)((u + 0x7FFFu + ((u >> 16) & 1u)) >> 16);
}

__device__ __forceinline__ float fast_exp2(float x) {
#if __has_builtin(__builtin_amdgcn_exp2f)
  return __builtin_amdgcn_exp2f(x);
#else
  return exp2f(x);
#endif
}

__device__ __forceinline__ int load_mask(const void* p, long i, int fmt) {
  if (fmt == 1) return (int)((const unsigned char*)p)[i];
  if (fmt == 2) return (int)(((const int*)p)[2 * i] != 0);
  return ((const int*)p)[i];
}

// ---------------------------------------------------------------------------
// prep: blocks 0..191 transpose Wk/Wv to bf16 [c][k]; block 192 detects mask
// layout (0=int32,1=u8,2=int64) and zeroes SV.
// ---------------------------------------------------------------------------
__global__ __launch_bounds__(256) void prep_kernel(
    const float* __restrict__ Wk, const float* __restrict__ Wv,
    const unsigned char* __restrict__ qm, unsigned short* __restrict__ WkT,
    unsigned short* __restrict__ WvT, int* __restrict__ flag,
    float* __restrict__ SV) {
  if (blockIdx.x < 192) {
    int idx = blockIdx.x * 256 + threadIdx.x;
    if (idx < 24576) {
      const int k = idx >> 5, c = idx & 31;
      WkT[c * 768 + k] = f2bf(Wk[idx]);
    } else {
      idx -= 24576;
      const int k = idx >> 5, c = idx & 31;
      WvT[c * 768 + k] = f2bf(Wv[idx]);
    }
  } else {
    __shared__ int any14, any47;
    SV[threadIdx.x] = 0.f;  // 256 = kB*32
    if (threadIdx.x == 0) { any14 = 0; any47 = 0; }
    __syncthreads();
    int l14 = 0, l47 = 0;
    for (int i = threadIdx.x; i < 16384; i += 256) {
      const unsigned char v = qm[i];
      if (v && (i & 3)) l14 = 1;
      if (v && ((i & 7) >= 4)) l47 = 1;
    }
    if (l14) atomicOr(&any14, 1);
    if (l47) atomicOr(&any47, 1);
    __syncthreads();
    if (threadIdx.x == 0) *flag = any14 ? 1 : (any47 ? 0 : 2);
  }
}

// ---------------------------------------------------------------------------
// K/V projection via MFMA (16 rows/block, 1 wave) + masked-V column sums
// (SV[b][e] += sum over masked rows) via global atomics.
// ---------------------------------------------------------------------------
__global__ __launch_bounds__(64) void proj_kv_kernel(
    const float* __restrict__ key, const unsigned short* __restrict__ WkT,
    const unsigned short* __restrict__ WvT, const void* __restrict__ kmask,
    const int* __restrict__ mflag, unsigned short* __restrict__ Kbf,
    unsigned short* __restrict__ Vt, float* __restrict__ SV) {
  const int t = threadIdx.x;
  const int r15 = t & 15, g = t >> 4;
  const int row = blockIdx.x * 16 + r15;
  const float* kp = &key[(size_t)row * kSUB];
  const f32x4 zf = {0.f, 0.f, 0.f, 0.f};
  f32x4 aK0 = zf, aK1 = zf, aV0 = zf, aV1 = zf;
#pragma unroll 4
  for (int ks = 0; ks < kSUB; ks += 32) {
    const f32x4 lo = *(const f32x4*)&kp[ks + g * 8];
    const f32x4 hi = *(const f32x4*)&kp[ks + g * 8 + 4];
    short8v a;
#pragma unroll
    for (int j = 0; j < 4; ++j) {
      a[j] = (short)f2bf(lo[j]);
      a[4 + j] = (short)f2bf(hi[j]);
    }
    const short8v bk0 = *(const short8v*)&WkT[(size_t)r15 * 768 + ks + g * 8];
    const short8v bk1 =
        *(const short8v*)&WkT[(size_t)(16 + r15) * 768 + ks + g * 8];
    const short8v bv0 = *(const short8v*)&WvT[(size_t)r15 * 768 + ks + g * 8];
    const short8v bv1 =
        *(const short8v*)&WvT[(size_t)(16 + r15) * 768 + ks + g * 8];
    aK0 = __builtin_amdgcn_mfma_f32_16x16x32_bf16(a, bk0, aK0, 0, 0, 0);
    aK1 = __builtin_amdgcn_mfma_f32_16x16x32_bf16(a, bk1, aK1, 0, 0, 0);
    aV0 = __builtin_amdgcn_mfma_f32_16x16x32_bf16(a, bv0, aV0, 0, 0, 0);
    aV1 = __builtin_amdgcn_mfma_f32_16x16x32_bf16(a, bv1, aV1, 0, 0, 0);
  }
  const int orow = blockIdx.x * 16 + g * 4;
  const int fmt = *mflag;
  float p0 = 0.f, p1 = 0.f;
#pragma unroll
  for (int jj = 0; jj < 4; ++jj) {
    const int r = orow + jj;
    Kbf[(size_t)r * 32 + r15] = f2bf(aK0[jj]);
    Kbf[(size_t)r * 32 + 16 + r15] = f2bf(aK1[jj]);
    const int bb = r >> 10, s = r & 1023;
    Vt[((size_t)bb * 32 + r15) * kS + s] = f2bf(aV0[jj]);
    Vt[((size_t)bb * 32 + 16 + r15) * kS + s] = f2bf(aV1[jj]);
    if (load_mask(kmask, (long)r, fmt)) {
      p0 += aV0[jj];
      p1 += aV1[jj];
    }
  }
  p0 += __shfl_xor(p0, 16);
  p0 += __shfl_xor(p0, 32);
  p1 += __shfl_xor(p1, 16);
  p1 += __shfl_xor(p1, 32);
  if (g == 0) {
    const int bb = (blockIdx.x * 16) >> 10;
    atomicAdd(&SV[bb * 32 + r15], p0);
    atomicAdd(&SV[bb * 32 + 16 + r15], p1);
  }
}

// ---------------------------------------------------------------------------
// Fused attention: 64 q-rows/block (4 tiles of 16), 512 threads (8 waves x
// 128 s-cols). PV runs on pre-min-shift d (bf16); min-shift applied as an
// exact f32 correction in the epilogue (Sum (d-rmin+eps)V = Sum dV -
// (rmin-eps)*SV). In-loop barriers drain lgkm only.
// ---------------------------------------------------------------------------
__global__ __launch_bounds__(512) void attn_kernel(
    const float* __restrict__ query, const float* __restrict__ Wq,
    const unsigned short* __restrict__ Kbf,
    const unsigned short* __restrict__ Vt, const void* __restrict__ qmask,
    const void* __restrict__ kmask, const float* __restrict__ lq1,
    const float* __restrict__ lk1, const float* __restrict__ lq2,
    const float* __restrict__ lk2, const float* __restrict__ rmsw,
    const float* __restrict__ Wo, const int* __restrict__ mflag,
    const float* __restrict__ SVg, float* __restrict__ out,
    float* __restrict__ diff) {
  __shared__ __align__(16) char ubuf[12288];  // {sWq 4KB + sQi 8KB} | pvacc
  __shared__ float sWo[32][32];
  __shared__ unsigned short qlds[64][40];
  __shared__ unsigned kmp_lds[256];
  __shared__ float reds[8][2][16];
  __shared__ float redn[8][16];
  __shared__ float rminS[64];
  __shared__ float svS[32];
  __shared__ float srw[32];
  __shared__ int qmS[64];
  __shared__ float slam;

  float* const sWq = (float*)ubuf;            // [32][32] k-major
  float* const sQi = (float*)(ubuf + 4096);   // [64][32]
  float* const pvacc = (float*)ubuf;          // [64][36] (9216 B)

  const int t = threadIdx.x;
  const int lane = t & 63;
  const int w = t >> 6;
  const int r15 = lane & 15;
  const int g = lane >> 4;
  const int b = blockIdx.x >> 6;
  const int rowbase = b * kL + (blockIdx.x & 63) * 64;
  const int kvb = b * kS;
  const int fmt = *mflag;

  // ---- stage (once per 64 rows) ----
  if (t < 256) {
    *(f32x4*)(sWq + 4 * t) = *(const f32x4*)(Wq + 4 * t);
    *(f32x4*)(&sWo[0][0] + 4 * t) = *(const f32x4*)(Wo + 4 * t);
    const long base = (long)kvb + 4 * t;
    const unsigned m0 = load_mask(kmask, base + 0, fmt) ? 1u : 0u;
    const unsigned m1 = load_mask(kmask, base + 1, fmt) ? 1u : 0u;
    const unsigned m2 = load_mask(kmask, base + 2, fmt) ? 1u : 0u;
    const unsigned m3 = load_mask(kmask, base + 3, fmt) ? 1u : 0u;
    kmp_lds[t] = m0 | (m1 << 8) | (m2 << 16) | (m3 << 24);
  }
  *(f32x4*)(sQi + 4 * t) = *(const f32x4*)(query + (size_t)rowbase * 32 + 4 * t);
  if (t < 64) qmS[t] = load_mask(qmask, (long)rowbase + t, fmt);
  if (t < 32) {
    srw[t] = rmsw[t];
    svS[t] = SVg[b * 32 + t];
  }
  if (t == 0) {
    float a = 0.f, c2 = 0.f;
#pragma unroll
    for (int i = 0; i < 16; ++i) {
      a += lq1[i] * lk1[i];
      c2 += lq2[i] * lk2[i];
    }
    slam = expf(a) - expf(c2) + kLamInit;
  }
  BAR_LGKM();

  // ---- fused Q projection: qlds[q][e] = bf16(dot * scale), 64 rows ----
#pragma unroll
  for (int p = 0; p < 4; ++p) {
    const int idx = t + 512 * p;
    const int row = idx >> 5, col = idx & 31;
    float a = 0.f;
#pragma unroll
    for (int k = 0; k < 32; ++k) a += sQi[row * 32 + k] * sWq[k * 32 + col];
    qlds[row][col] = f2bf(a * kQScale);
  }
  BAR_LGKM();

  // ---- zero pvacc (overlays sWq/sQi) ----
  for (int i = t; i < 64 * 36; i += 512) pvacc[i] = 0.f;

  const int wb = w * 128;  // this wave's S-range base
  const short8v z8 = {0, 0, 0, 0, 0, 0, 0, 0};
  const f32x4 zf = {0.f, 0.f, 0.f, 0.f};
  const float lam = slam;

  unsigned kmp[8];
#pragma unroll
  for (int c = 0; c < 8; ++c) kmp[c] = kmp_lds[(wb >> 2) + c * 4 + g];

  const int sl0 = ((g & 1) << 5) + r15;  // PV gather source lanes
  const int sl1 = sl0 + 16;
  const bool hi = (g >> 1) != 0;

  for (int qt = 0; qt < 4; ++qt) {
    const int lr0 = qt * 16;
    const int rb = rowbase + lr0;

    short8v qa0 = z8, qa1 = z8;
    if (lane < 32) {
      qa0 = *(const short8v*)&qlds[lr0 + r15][g * 8];
      qa1 = *(const short8v*)&qlds[lr0 + r15][16 + g * 8];
    }

    // ---- QK^T swapped: D[s = g*4+jj][q = r15] ----
    f32x4 acc[8][2];
#pragma unroll
    for (int c = 0; c < 8; ++c) {
      const unsigned short* kr =
          &Kbf[((size_t)(kvb + wb + c * 16 + r15)) * 32];
      short8v kb0 = z8, kb1 = z8;
      if (lane < 32) {
        kb0 = *(const short8v*)&kr[g * 8];
        kb1 = *(const short8v*)&kr[16 + g * 8];
      }
      acc[c][0] =
          __builtin_amdgcn_mfma_f32_16x16x32_bf16(kb0, qa0, zf, 0, 0, 0);
      acc[c][1] =
          __builtin_amdgcn_mfma_f32_16x16x32_bf16(kb1, qa1, zf, 0, 0, 0);
    }
    const int qm = qmS[lr0 + r15];

    // ---- exp2(v - 64) masked, in place + tree sum ----
#pragma unroll
    for (int h = 0; h < 2; ++h) {
      float s4[4] = {0.f, 0.f, 0.f, 0.f};
#pragma unroll
      for (int c = 0; c < 8; ++c) {
        f32x4 e;
#pragma unroll
        for (int jj = 0; jj < 4; ++jj) {
          float ev = fast_exp2(acc[c][h][jj] - kShift);
          e[jj] = ((kmp[c] >> (8 * jj)) & 1u) ? ev : 0.f;
        }
        acc[c][h] = e;
        s4[c & 3] += (e[0] + e[1]) + (e[2] + e[3]);
      }
      float s = (s4[0] + s4[1]) + (s4[2] + s4[3]);
      s += __shfl_xor(s, 16);
      s += __shfl_xor(s, 32);
      if (lane < 16) reds[w][h][lane] = s;
    }
    BAR_LGKM();  // B1

    float fi[2];
#pragma unroll
    for (int h = 0; h < 2; ++h) {
      const float a0 = reds[0][h][r15] + reds[1][h][r15];
      const float a1 = reds[2][h][r15] + reds[3][h][r15];
      const float a2 = reds[4][h][r15] + reds[5][h][r15];
      const float a3 = reds[6][h][r15] + reds[7][h][r15];
      fi[h] = 1.f / ((a0 + a1) + (a2 + a3) + 1e-37f);
    }

    // ---- d = a0 - lam*a1 (in place) + pack bf16(d) for PV ----
    const float f0 = fi[0], nf1 = -lam * fi[1];
    unsigned pkx[8], pky[8];
#pragma unroll
    for (int c = 0; c < 8; ++c) {
      f32x4 d;
#pragma unroll
      for (int jj = 0; jj < 4; ++jj)
        d[jj] = fmaf(acc[c][0][jj], f0, nf1 * acc[c][1][jj]);
      acc[c][0] = d;
      pkx[c] = (unsigned)f2bf(d[0]) | ((unsigned)f2bf(d[1]) << 16);
      pky[c] = (unsigned)f2bf(d[2]) | ((unsigned)f2bf(d[3]) << 16);
    }

    // ---- PV on pre-shift d (independent of rmin) ----
    f32x4 pv[2] = {zf, zf};
#pragma unroll
    for (int kc = 0; kc < 4; ++kc) {
      const unsigned x0a = (unsigned)__shfl((int)pkx[2 * kc], sl0);
      const unsigned y0a = (unsigned)__shfl((int)pky[2 * kc], sl0);
      const unsigned x0b = (unsigned)__shfl((int)pkx[2 * kc], sl1);
      const unsigned y0b = (unsigned)__shfl((int)pky[2 * kc], sl1);
      const unsigned x1a = (unsigned)__shfl((int)pkx[2 * kc + 1], sl0);
      const unsigned y1a = (unsigned)__shfl((int)pky[2 * kc + 1], sl0);
      const unsigned x1b = (unsigned)__shfl((int)pkx[2 * kc + 1], sl1);
      const unsigned y1b = (unsigned)__shfl((int)pky[2 * kc + 1], sl1);
      uint4v avw;
      avw.x = hi ? x1a : x0a;
      avw.y = hi ? y1a : y0a;
      avw.z = hi ? x1b : x0b;
      avw.w = hi ? y1b : y0b;
      const short8v av = *(const short8v*)&avw;
      const int soff = wb + kc * 32 + g * 8;
#pragma unroll
      for (int n = 0; n < 2; ++n) {
        const short8v bv =
            *(const short8v*)&Vt[((size_t)(b * 32 + n * 16 + r15)) * kS + soff];
        pv[n] = __builtin_amdgcn_mfma_f32_16x16x32_bf16(av, bv, pv[n], 0, 0, 0);
      }
    }
#pragma unroll
    for (int n = 0; n < 2; ++n)
#pragma unroll
      for (int jj = 0; jj < 4; ++jj)
        atomicAdd(&pvacc[(lr0 + g * 4 + jj) * 36 + n * 16 + r15], pv[n][jj]);

    // ---- row-min of d (tree) ----
    {
      float cmn[8];
#pragma unroll
      for (int c = 0; c < 8; ++c)
        cmn[c] = fminf(fminf(acc[c][0][0], acc[c][0][1]),
                       fminf(acc[c][0][2], acc[c][0][3]));
      float dm = fminf(fminf(fminf(cmn[0], cmn[1]), fminf(cmn[2], cmn[3])),
                       fminf(fminf(cmn[4], cmn[5]), fminf(cmn[6], cmn[7])));
      dm = fminf(dm, __shfl_xor(dm, 16));
      dm = fminf(dm, __shfl_xor(dm, 32));
      if (lane < 16) redn[w][lane] = dm;
    }
    BAR_LGKM();  // B2

    float rmin;
    {
      const float a0 = fminf(redn[0][r15], redn[1][r15]);
      const float a1 = fminf(redn[2][r15], redn[3][r15]);
      const float a2 = fminf(redn[4][r15], redn[5][r15]);
      const float a3 = fminf(redn[6][r15], redn[7][r15]);
      rmin = fminf(fminf(a0, a1), fminf(a2, a3));
    }
    if (t < 16) rminS[lr0 + t] = rmin;

    // ---- diff = (qm&&km) ? d - rmin + eps : 0 ; fire-and-forget stores ----
#pragma unroll
    for (int c = 0; c < 8; ++c) {
      f32x4 fd;
#pragma unroll
      for (int jj = 0; jj < 4; ++jj) {
        const int km = (kmp[c] >> (8 * jj)) & 1u;
        fd[jj] = (qm && km) ? acc[c][0][jj] - rmin + 1e-5f : 0.f;
      }
      const int scol = wb + c * 16 + g * 4;
      *(f32x4*)&diff[((size_t)(rb + r15)) * kS + scol] = fd;
    }
  }
  BAR_LGKM();  // pvacc/rminS visible; diff stores still in flight

  // ---- epilogue: correction + RMSNorm + @Wo, 4 interleaved row-passes ----
  {
    const int row0 = t >> 5;
    const int col = t & 31;
    const int half = lane & 32;
    float nx[4], o[4] = {0.f, 0.f, 0.f, 0.f};
#pragma unroll
    for (int p = 0; p < 4; ++p) {
      const int row = p * 16 + row0;
      float ao = pvacc[row * 36 + col] - (rminS[row] - 1e-5f) * svS[col];
      if (!qmS[row]) ao = 0.f;
      float ss = ao * ao;
#pragma unroll
      for (int off = 16; off >= 1; off >>= 1) ss += __shfl_xor(ss, off);
      const float rms = 1.0f / sqrtf(ss * (1.f / 32.f) + 1e-5f);
      nx[p] = ao * rms * srw[col] * kOutScale;
    }
#pragma unroll
    for (int e = 0; e < 32; ++e) {
      const float we = sWo[e][col];
#pragma unroll
      for (int p = 0; p < 4; ++p) o[p] += __shfl(nx[p], half + e) * we;
    }
#pragma unroll
    for (int p = 0; p < 4; ++p)
      out[((size_t)(rowbase + p * 16 + row0)) * 32 + col] = o[p];
  }
}

}  // namespace

extern "C" void kernel_launch(void* const* d_in, const int* in_sizes, int n_in,
                              void* d_out, int out_size, void* d_ws,
                              size_t ws_size, hipStream_t stream) {
  const float* query = (const float*)d_in[0];
  const float* key = (const float*)d_in[1];
  const void* qmask = d_in[2];
  const void* kmask = d_in[3];
  const float* Wq = (const float*)d_in[4];
  const float* Wk = (const float*)d_in[5];
  const float* Wv = (const float*)d_in[6];
  const float* Wo = (const float*)d_in[7];
  const float* lq1 = (const float*)d_in[8];
  const float* lk1 = (const float*)d_in[9];
  const float* lq2 = (const float*)d_in[10];
  const float* lk2 = (const float*)d_in[11];
  const float* rmsw = (const float*)d_in[12];

  unsigned short* Kbf = (unsigned short*)d_ws;            // [B*S,32]
  unsigned short* Vt = Kbf + (size_t)kB * kS * 32;        // [B,32,S]
  unsigned short* WkT = Vt + (size_t)kB * kS * 32;        // [32,768]
  unsigned short* WvT = WkT + (size_t)32 * 768;           // [32,768]
  float* SV = (float*)(WvT + (size_t)32 * 768);           // [B,32]
  int* mflag = (int*)(SV + kB * 32);

  float* outp = (float*)d_out;
  float* diffp = outp + (size_t)kB * kL * 32;

  prep_kernel<<<dim3(193), dim3(256), 0, stream>>>(
      Wk, Wv, (const unsigned char*)qmask, WkT, WvT, mflag, SV);
  proj_kv_kernel<<<dim3(kB * kS / 16), dim3(64), 0, stream>>>(
      key, WkT, WvT, kmask, mflag, Kbf, Vt, SV);
  attn_kernel<<<dim3(kB * (kL / 64)), dim3(512), 0, stream>>>(
      query, Wq, Kbf, Vt, qmask, kmask, lq1, lk1, lq2, lk2, rmsw, Wo, mflag,
      SV, outp, diffp);
}

// Round 10
// 125.645 us; speedup vs baseline: 1.2263x; 1.2263x over previous
//
#include <hip/hip_runtime.h>

namespace {

typedef __attribute__((ext_vector_type(8))) short short8v;
typedef __attribute__((ext_vector_type(4))) float f32x4;
typedef __attribute__((ext_vector_type(4))) unsigned int uint4v;

constexpr int kB = 8;
constexpr int kS = 1024;
constexpr int kSUB = 768;
constexpr int kL = 4096;                                   // P*G
constexpr float kQScale = 0.25f * 1.44269504088896340736f; // SCALING*log2(e)
constexpr float kLamInit = 0.2f;
constexpr float kOutScale = 0.8f;
constexpr float kShift = 64.f;  // fixed softmax shift (log2 units); |score|<<60

// LDS-only barrier: global stores stay in flight across it. Used ONLY after
// the last global load has been issued (loop body has no global loads).
#define BAR_LGKM() asm volatile("s_waitcnt lgkmcnt(0)\ns_barrier" ::: "memory")

__device__ __forceinline__ unsigned short f2bf(float x) {
  unsigned u = __float_as_uint(x);
  return (unsigned short)((u + 0x7FFFu + ((u >> 16) & 1u)) >> 16);
}

__device__ __forceinline__ float fast_exp2(float x) {
#if __has_builtin(__builtin_amdgcn_exp2f)
  return __builtin_amdgcn_exp2f(x);
#else
  return exp2f(x);
#endif
}

__device__ __forceinline__ int load_mask(const void* p, long i, int fmt) {
  if (fmt == 1) return (int)((const unsigned char*)p)[i];
  if (fmt == 2) return (int)(((const int*)p)[2 * i] != 0);
  return ((const int*)p)[i];
}

// ---------------------------------------------------------------------------
// prep: blocks 0..191 transpose Wk/Wv to bf16 [c][k]; block 192 detects mask
// layout (0=int32,1=u8,2=int64).
// ---------------------------------------------------------------------------
__global__ __launch_bounds__(256) void prep_kernel(
    const float* __restrict__ Wk, const float* __restrict__ Wv,
    const unsigned char* __restrict__ qm, unsigned short* __restrict__ WkT,
    unsigned short* __restrict__ WvT, int* __restrict__ flag) {
  if (blockIdx.x < 192) {
    int idx = blockIdx.x * 256 + threadIdx.x;
    if (idx < 24576) {
      const int k = idx >> 5, c = idx & 31;
      WkT[c * 768 + k] = f2bf(Wk[idx]);
    } else {
      idx -= 24576;
      const int k = idx >> 5, c = idx & 31;
      WvT[c * 768 + k] = f2bf(Wv[idx]);
    }
  } else {
    __shared__ int any14, any47;
    if (threadIdx.x == 0) { any14 = 0; any47 = 0; }
    __syncthreads();
    int l14 = 0, l47 = 0;
    for (int i = threadIdx.x; i < 16384; i += 256) {
      const unsigned char v = qm[i];
      if (v && (i & 3)) l14 = 1;
      if (v && ((i & 7) >= 4)) l47 = 1;
    }
    if (l14) atomicOr(&any14, 1);
    if (l47) atomicOr(&any47, 1);
    __syncthreads();
    if (threadIdx.x == 0) *flag = any14 ? 1 : (any47 ? 0 : 2);
  }
}

// ---------------------------------------------------------------------------
// K/V projection via MFMA: 16 rows/block, 64 threads (1 wave), K=768.
// Kbf[r][e]; Vt[b][e][s].
// ---------------------------------------------------------------------------
__global__ __launch_bounds__(64) void proj_kv_kernel(
    const float* __restrict__ key, const unsigned short* __restrict__ WkT,
    const unsigned short* __restrict__ WvT, unsigned short* __restrict__ Kbf,
    unsigned short* __restrict__ Vt) {
  const int t = threadIdx.x;
  const int r15 = t & 15, g = t >> 4;
  const int row = blockIdx.x * 16 + r15;
  const float* kp = &key[(size_t)row * kSUB];
  const f32x4 zf = {0.f, 0.f, 0.f, 0.f};
  f32x4 aK0 = zf, aK1 = zf, aV0 = zf, aV1 = zf;
#pragma unroll 4
  for (int ks = 0; ks < kSUB; ks += 32) {
    const f32x4 lo = *(const f32x4*)&kp[ks + g * 8];
    const f32x4 hi = *(const f32x4*)&kp[ks + g * 8 + 4];
    short8v a;
#pragma unroll
    for (int j = 0; j < 4; ++j) {
      a[j] = (short)f2bf(lo[j]);
      a[4 + j] = (short)f2bf(hi[j]);
    }
    const short8v bk0 = *(const short8v*)&WkT[(size_t)r15 * 768 + ks + g * 8];
    const short8v bk1 =
        *(const short8v*)&WkT[(size_t)(16 + r15) * 768 + ks + g * 8];
    const short8v bv0 = *(const short8v*)&WvT[(size_t)r15 * 768 + ks + g * 8];
    const short8v bv1 =
        *(const short8v*)&WvT[(size_t)(16 + r15) * 768 + ks + g * 8];
    aK0 = __builtin_amdgcn_mfma_f32_16x16x32_bf16(a, bk0, aK0, 0, 0, 0);
    aK1 = __builtin_amdgcn_mfma_f32_16x16x32_bf16(a, bk1, aK1, 0, 0, 0);
    aV0 = __builtin_amdgcn_mfma_f32_16x16x32_bf16(a, bv0, aV0, 0, 0, 0);
    aV1 = __builtin_amdgcn_mfma_f32_16x16x32_bf16(a, bv1, aV1, 0, 0, 0);
  }
  const int orow = blockIdx.x * 16 + g * 4;
#pragma unroll
  for (int jj = 0; jj < 4; ++jj) {
    const int r = orow + jj;
    Kbf[(size_t)r * 32 + r15] = f2bf(aK0[jj]);
    Kbf[(size_t)r * 32 + 16 + r15] = f2bf(aK1[jj]);
    const int bb = r >> 10, s = r & 1023;
    Vt[((size_t)bb * 32 + r15) * kS + s] = f2bf(aV0[jj]);
    Vt[((size_t)bb * 32 + 16 + r15) * kS + s] = f2bf(aV1[jj]);
  }
}

// ---------------------------------------------------------------------------
// Fused attention: 64 q-rows/block (4 tiles of 16), 512 threads (8 waves x
// 128 s-cols). ALL global loads (K, Vt fragments) are preloaded into
// registers before the tile loop; the loop issues only fire-and-forget diff
// stores + LDS ops, so stores never block anything (in-order vmcnt).
// ---------------------------------------------------------------------------
__global__ __launch_bounds__(512) void attn_kernel(
    const float* __restrict__ query, const float* __restrict__ Wq,
    const unsigned short* __restrict__ Kbf,
    const unsigned short* __restrict__ Vt, const void* __restrict__ qmask,
    const void* __restrict__ kmask, const float* __restrict__ lq1,
    const float* __restrict__ lk1, const float* __restrict__ lq2,
    const float* __restrict__ lk2, const float* __restrict__ rmsw,
    const float* __restrict__ Wo, const int* __restrict__ mflag,
    float* __restrict__ out, float* __restrict__ diff) {
  __shared__ __align__(16) char ubuf[12288];  // {sWq 4KB + sQi 8KB} | pvacc
  __shared__ float sWo[32][32];
  __shared__ unsigned short qlds[64][40];
  __shared__ unsigned kmp_lds[256];
  __shared__ float reds[8][2][16];
  __shared__ float redn[8][16];
  __shared__ float srw[32];
  __shared__ int qmS[64];
  __shared__ float slam;

  float* const sWq = (float*)ubuf;            // [32][32] k-major
  float* const sQi = (float*)(ubuf + 4096);   // [64][32]
  float* const pvacc = (float*)ubuf;          // [64][36] (9216 B)

  const int t = threadIdx.x;
  const int lane = t & 63;
  const int w = t >> 6;
  const int r15 = lane & 15;
  const int g = lane >> 4;
  const int b = blockIdx.x >> 6;
  const int rowbase = b * kL + (blockIdx.x & 63) * 64;
  const int kvb = b * kS;
  const int fmt = *mflag;

  // ---- stage (once per 64 rows) ----
  if (t < 256) {
    *(f32x4*)(sWq + 4 * t) = *(const f32x4*)(Wq + 4 * t);
    *(f32x4*)(&sWo[0][0] + 4 * t) = *(const f32x4*)(Wo + 4 * t);
    const long base = (long)kvb + 4 * t;
    const unsigned m0 = load_mask(kmask, base + 0, fmt) ? 1u : 0u;
    const unsigned m1 = load_mask(kmask, base + 1, fmt) ? 1u : 0u;
    const unsigned m2 = load_mask(kmask, base + 2, fmt) ? 1u : 0u;
    const unsigned m3 = load_mask(kmask, base + 3, fmt) ? 1u : 0u;
    kmp_lds[t] = m0 | (m1 << 8) | (m2 << 16) | (m3 << 24);
  }
  *(f32x4*)(sQi + 4 * t) = *(const f32x4*)(query + (size_t)rowbase * 32 + 4 * t);
  if (t < 64) qmS[t] = load_mask(qmask, (long)rowbase + t, fmt);
  if (t < 32) srw[t] = rmsw[t];
  if (t == 0) {
    float a = 0.f, c2 = 0.f;
#pragma unroll
    for (int i = 0; i < 16; ++i) {
      a += lq1[i] * lk1[i];
      c2 += lq2[i] * lk2[i];
    }
    slam = expf(a) - expf(c2) + kLamInit;
  }
  __syncthreads();

  const int wb = w * 128;  // this wave's S-range base
  const short8v z8 = {0, 0, 0, 0, 0, 0, 0, 0};
  const f32x4 zf = {0.f, 0.f, 0.f, 0.f};

  // ---- preload ALL K fragments (shared by every q-tile) ----
  short8v kb[8][2];
#pragma unroll
  for (int c = 0; c < 8; ++c) {
    const unsigned short* kr = &Kbf[((size_t)(kvb + wb + c * 16 + r15)) * 32];
    if (lane < 32) {
      kb[c][0] = *(const short8v*)&kr[g * 8];
      kb[c][1] = *(const short8v*)&kr[16 + g * 8];
    } else {
      kb[c][0] = z8;
      kb[c][1] = z8;
    }
  }
  // ---- preload ALL Vt fragments (shared by every q-tile) ----
  short8v vt[4][2];
#pragma unroll
  for (int kc = 0; kc < 4; ++kc) {
    const int soff = wb + kc * 32 + g * 8;
#pragma unroll
    for (int n = 0; n < 2; ++n)
      vt[kc][n] =
          *(const short8v*)&Vt[((size_t)(b * 32 + n * 16 + r15)) * kS + soff];
  }

  // ---- fused Q projection: qlds[q][e] = bf16(dot * scale), 64 rows ----
#pragma unroll
  for (int p = 0; p < 4; ++p) {
    const int idx = t + 512 * p;
    const int row = idx >> 5, col = idx & 31;
    float a = 0.f;
#pragma unroll
    for (int k = 0; k < 32; ++k) a += sQi[row * 32 + k] * sWq[k * 32 + col];
    qlds[row][col] = f2bf(a * kQScale);
  }
  __syncthreads();  // also drains the kb/vt preloads (no stores yet)

  // ---- zero pvacc (overlays sWq/sQi) ----
  for (int i = t; i < 64 * 36; i += 512) pvacc[i] = 0.f;

  const float lam = slam;
  unsigned kmp[8];
#pragma unroll
  for (int c = 0; c < 8; ++c) kmp[c] = kmp_lds[(wb >> 2) + c * 4 + g];

  const int sl0 = ((g & 1) << 5) + r15;  // PV gather source lanes
  const int sl1 = sl0 + 16;
  const bool hi = (g >> 1) != 0;

  for (int qt = 0; qt < 4; ++qt) {
    const int lr0 = qt * 16;
    const int rb = rowbase + lr0;

    short8v qa0 = z8, qa1 = z8;
    if (lane < 32) {
      qa0 = *(const short8v*)&qlds[lr0 + r15][g * 8];
      qa1 = *(const short8v*)&qlds[lr0 + r15][16 + g * 8];
    }

    // ---- QK^T swapped: D[s = g*4+jj][q = r15] (registers only) ----
    f32x4 acc[8][2];
#pragma unroll
    for (int c = 0; c < 8; ++c) {
      acc[c][0] =
          __builtin_amdgcn_mfma_f32_16x16x32_bf16(kb[c][0], qa0, zf, 0, 0, 0);
      acc[c][1] =
          __builtin_amdgcn_mfma_f32_16x16x32_bf16(kb[c][1], qa1, zf, 0, 0, 0);
    }
    const int qm = qmS[lr0 + r15];

    // ---- exp2(v - 64) masked, in place + tree sum ----
#pragma unroll
    for (int h = 0; h < 2; ++h) {
      float s4[4] = {0.f, 0.f, 0.f, 0.f};
#pragma unroll
      for (int c = 0; c < 8; ++c) {
        f32x4 e;
#pragma unroll
        for (int jj = 0; jj < 4; ++jj) {
          float ev = fast_exp2(acc[c][h][jj] - kShift);
          e[jj] = ((kmp[c] >> (8 * jj)) & 1u) ? ev : 0.f;
        }
        acc[c][h] = e;
        s4[c & 3] += (e[0] + e[1]) + (e[2] + e[3]);
      }
      float s = (s4[0] + s4[1]) + (s4[2] + s4[3]);
      s += __shfl_xor(s, 16);
      s += __shfl_xor(s, 32);
      if (lane < 16) reds[w][h][lane] = s;
    }
    BAR_LGKM();  // B1 (LDS only; diff stores from prior tiles stay in flight)

    float fi[2];
#pragma unroll
    for (int h = 0; h < 2; ++h) {
      const float a0 = reds[0][h][r15] + reds[1][h][r15];
      const float a1 = reds[2][h][r15] + reds[3][h][r15];
      const float a2 = reds[4][h][r15] + reds[5][h][r15];
      const float a3 = reds[6][h][r15] + reds[7][h][r15];
      fi[h] = 1.f / ((a0 + a1) + (a2 + a3) + 1e-37f);
    }

    // ---- d = a0 - lam*a1 (in place) + tree min ----
    const float f0 = fi[0], nf1 = -lam * fi[1];
    {
      float cmn[8];
#pragma unroll
      for (int c = 0; c < 8; ++c) {
        f32x4 d;
#pragma unroll
        for (int jj = 0; jj < 4; ++jj)
          d[jj] = fmaf(acc[c][0][jj], f0, nf1 * acc[c][1][jj]);
        acc[c][0] = d;
        cmn[c] = fminf(fminf(d[0], d[1]), fminf(d[2], d[3]));
      }
      float dm = fminf(fminf(fminf(cmn[0], cmn[1]), fminf(cmn[2], cmn[3])),
                       fminf(fminf(cmn[4], cmn[5]), fminf(cmn[6], cmn[7])));
      dm = fminf(dm, __shfl_xor(dm, 16));
      dm = fminf(dm, __shfl_xor(dm, 32));
      if (lane < 16) redn[w][lane] = dm;
    }
    BAR_LGKM();  // B2

    float rmin;
    {
      const float a0 = fminf(redn[0][r15], redn[1][r15]);
      const float a1 = fminf(redn[2][r15], redn[3][r15]);
      const float a2 = fminf(redn[4][r15], redn[5][r15]);
      const float a3 = fminf(redn[6][r15], redn[7][r15]);
      rmin = fminf(fminf(a0, a1), fminf(a2, a3));
    }

    // ---- fd; fire-and-forget diff stores; pack bf16 for PV ----
    unsigned pkx[8], pky[8];
#pragma unroll
    for (int c = 0; c < 8; ++c) {
      f32x4 fd;
#pragma unroll
      for (int jj = 0; jj < 4; ++jj) {
        const int km = (kmp[c] >> (8 * jj)) & 1u;
        fd[jj] = (qm && km) ? acc[c][0][jj] - rmin + 1e-5f : 0.f;
      }
      const int scol = wb + c * 16 + g * 4;
      *(f32x4*)&diff[((size_t)(rb + r15)) * kS + scol] = fd;
      pkx[c] = (unsigned)f2bf(fd[0]) | ((unsigned)f2bf(fd[1]) << 16);
      pky[c] = (unsigned)f2bf(fd[2]) | ((unsigned)f2bf(fd[3]) << 16);
    }

    // ---- PV: A-frag via in-wave shfl; B = preloaded vt (no loads) ----
    f32x4 pv[2] = {zf, zf};
#pragma unroll
    for (int kc = 0; kc < 4; ++kc) {
      const unsigned x0a = (unsigned)__shfl((int)pkx[2 * kc], sl0);
      const unsigned y0a = (unsigned)__shfl((int)pky[2 * kc], sl0);
      const unsigned x0b = (unsigned)__shfl((int)pkx[2 * kc], sl1);
      const unsigned y0b = (unsigned)__shfl((int)pky[2 * kc], sl1);
      const unsigned x1a = (unsigned)__shfl((int)pkx[2 * kc + 1], sl0);
      const unsigned y1a = (unsigned)__shfl((int)pky[2 * kc + 1], sl0);
      const unsigned x1b = (unsigned)__shfl((int)pkx[2 * kc + 1], sl1);
      const unsigned y1b = (unsigned)__shfl((int)pky[2 * kc + 1], sl1);
      uint4v avw;
      avw.x = hi ? x1a : x0a;
      avw.y = hi ? y1a : y0a;
      avw.z = hi ? x1b : x0b;
      avw.w = hi ? y1b : y0b;
      const short8v av = *(const short8v*)&avw;
#pragma unroll
      for (int n = 0; n < 2; ++n)
        pv[n] =
            __builtin_amdgcn_mfma_f32_16x16x32_bf16(av, vt[kc][n], pv[n], 0, 0, 0);
    }
#pragma unroll
    for (int n = 0; n < 2; ++n)
#pragma unroll
      for (int jj = 0; jj < 4; ++jj)
        atomicAdd(&pvacc[(lr0 + g * 4 + jj) * 36 + n * 16 + r15], pv[n][jj]);
  }
  BAR_LGKM();  // pvacc visible; diff stores still draining

  // ---- epilogue: RMSNorm + @Wo, 4 interleaved row-passes (ILP) ----
  {
    const int row0 = t >> 5;
    const int col = t & 31;
    const int half = lane & 32;
    float nx[4], o[4] = {0.f, 0.f, 0.f, 0.f};
#pragma unroll
    for (int p = 0; p < 4; ++p) {
      const int row = p * 16 + row0;
      const float ao = pvacc[row * 36 + col];
      float ss = ao * ao;
#pragma unroll
      for (int off = 16; off >= 1; off >>= 1) ss += __shfl_xor(ss, off);
      const float rms = 1.0f / sqrtf(ss * (1.f / 32.f) + 1e-5f);
      nx[p] = ao * rms * srw[col] * kOutScale;
    }
#pragma unroll
    for (int e = 0; e < 32; ++e) {
      const float we = sWo[e][col];
#pragma unroll
      for (int p = 0; p < 4; ++p) o[p] += __shfl(nx[p], half + e) * we;
    }
#pragma unroll
    for (int p = 0; p < 4; ++p)
      out[((size_t)(rowbase + p * 16 + row0)) * 32 + col] = o[p];
  }
}

}  // namespace

extern "C" void kernel_launch(void* const* d_in, const int* in_sizes, int n_in,
                              void* d_out, int out_size, void* d_ws,
                              size_t ws_size, hipStream_t stream) {
  const float* query = (const float*)d_in[0];
  const float* key = (const float*)d_in[1];
  const void* qmask = d_in[2];
  const void* kmask = d_in[3];
  const float* Wq = (const float*)d_in[4];
  const float* Wk = (const float*)d_in[5];
  const float* Wv = (const float*)d_in[6];
  const float* Wo = (const float*)d_in[7];
  const float* lq1 = (const float*)d_in[8];
  const float* lk1 = (const float*)d_in[9];
  const float* lq2 = (const float*)d_in[10];
  const float* lk2 = (const float*)d_in[11];
  const float* rmsw = (const float*)d_in[12];

  unsigned short* Kbf = (unsigned short*)d_ws;            // [B*S,32]
  unsigned short* Vt = Kbf + (size_t)kB * kS * 32;        // [B,32,S]
  unsigned short* WkT = Vt + (size_t)kB * kS * 32;        // [32,768]
  unsigned short* WvT = WkT + (size_t)32 * 768;           // [32,768]
  int* mflag = (int*)(WvT + (size_t)32 * 768);

  float* outp = (float*)d_out;
  float* diffp = outp + (size_t)kB * kL * 32;

  prep_kernel<<<dim3(193), dim3(256), 0, stream>>>(
      Wk, Wv, (const unsigned char*)qmask, WkT, WvT, mflag);
  proj_kv_kernel<<<dim3(kB * kS / 16), dim3(64), 0, stream>>>(key, WkT, WvT,
                                                              Kbf, Vt);
  attn_kernel<<<dim3(kB * (kL / 64)), dim3(512), 0, stream>>>(
      query, Wq, Kbf, Vt, qmask, kmask, lq1, lk1, lq2, lk2, rmsw, Wo, mflag,
      outp, diffp);
}